// Round 1
// baseline (540.037 us; speedup 1.0000x reference)
//
#include <hip/hip_runtime.h>

// TransformerBlock on MI355X — round 0 baseline.
// bf16 MFMA GEMMs (m97 structure), fused-RoPE QKV epilogue, 1-wave MFMA flash attention.

typedef __attribute__((ext_vector_type(8))) short short8;
typedef __attribute__((ext_vector_type(4))) float f32x4;

#define DEV __device__ __forceinline__

DEV unsigned short f2b(float f) {
  unsigned int u = __builtin_bit_cast(unsigned int, f);
  unsigned int r = u + 0x7fffu + ((u >> 16) & 1u);
  return (unsigned short)(r >> 16);
}
DEV float b2f(unsigned short h) {
  return __builtin_bit_cast(float, ((unsigned int)h) << 16);
}
DEV f32x4 MFMA(short8 a, short8 b, f32x4 c) {
  return __builtin_amdgcn_mfma_f32_16x16x32_bf16(a, b, c, 0, 0, 0);
}
DEV void gload16(const void* g, void* lds) {
  __builtin_amdgcn_global_load_lds((const __attribute__((address_space(1))) void*)g,
                                   (__attribute__((address_space(3))) void*)lds, 16, 0, 0);
}

// ---------------- f32 -> bf16 weight conversion ----------------
__global__ __launch_bounds__(256) void cvt_k(const float* __restrict__ src,
                                             unsigned short* __restrict__ dst, int n) {
  int i = (blockIdx.x * 256 + threadIdx.x) * 4;
  if (i + 3 < n) {
    float4 v = *(const float4*)(src + i);
    ushort4 o;
    o.x = f2b(v.x); o.y = f2b(v.y); o.z = f2b(v.z); o.w = f2b(v.w);
    *(ushort4*)(dst + i) = o;
  } else {
    for (int c = 0; c < 4 && i + c < n; ++c) dst[i + c] = f2b(src[i + c]);
  }
}

// ---------------- RMSNorm: f32 in, bf16 out (rows of 1024) ----------------
__global__ __launch_bounds__(256) void rms_k(const float* __restrict__ x,
                                             const float* __restrict__ g,
                                             unsigned short* __restrict__ out) {
  const int row = blockIdx.x;
  const int t = threadIdx.x;
  const float4 v = *(const float4*)(x + (size_t)row * 1024 + t * 4);
  float ss = v.x * v.x + v.y * v.y + v.z * v.z + v.w * v.w;
#pragma unroll
  for (int m = 32; m >= 1; m >>= 1) ss += __shfl_xor(ss, m, 64);
  __shared__ float red[4];
  if ((t & 63) == 0) red[t >> 6] = ss;
  __syncthreads();
  float tot = red[0] + red[1] + red[2] + red[3];
  float inv = rsqrtf(tot * (1.0f / 1024.0f) + 1e-5f);
  ushort4 o;
  o.x = f2b(v.x * inv * g[t * 4 + 0]);
  o.y = f2b(v.y * inv * g[t * 4 + 1]);
  o.z = f2b(v.z * inv * g[t * 4 + 2]);
  o.w = f2b(v.w * inv * g[t * 4 + 3]);
  *(ushort4*)(out + (size_t)row * 1024 + t * 4) = o;
}

// ---------------- GEMM: C[M][N] = A[M][K] * B[N][K]^T, bf16 in, MFMA ----------------
// MODE 0: QKV scatter with fused RoPE -> q/k/v (B,H,L,DH) bf16
// MODE 1: outF = resid + acc (f32)
// MODE 2: dual B (w1,w3): outH = bf16(silu(acc)*acc2)
template <int MODE>
__global__ __launch_bounds__(256) void gemm_bt(
    const unsigned short* __restrict__ A, const unsigned short* __restrict__ B0,
    const unsigned short* __restrict__ B1, int M, int N, int K,
    float* __restrict__ outF, const float* __restrict__ resid,
    unsigned short* __restrict__ q, unsigned short* __restrict__ k2,
    unsigned short* __restrict__ v, unsigned short* __restrict__ outH) {
  __shared__ __align__(16) unsigned short As[128 * 32];
  __shared__ __align__(16) unsigned short Bs[128 * 32];
  __shared__ __align__(16) unsigned short Bs2[(MODE == 2) ? 128 * 32 : 8];
  const int t = threadIdx.x;
  const int wv = t >> 6, ln = t & 63;
  const int l15 = ln & 15, grp = ln >> 4;
  const int wr = wv >> 1, wc = wv & 1;
  const int m0 = blockIdx.y * 128, n0 = blockIdx.x * 128;

  f32x4 acc[4][4];
  f32x4 acc2[(MODE == 2) ? 4 : 1][(MODE == 2) ? 4 : 1];
#pragma unroll
  for (int mm = 0; mm < 4; ++mm)
#pragma unroll
    for (int nn = 0; nn < 4; ++nn) acc[mm][nn] = (f32x4){0.f, 0.f, 0.f, 0.f};
  if constexpr (MODE == 2) {
#pragma unroll
    for (int mm = 0; mm < 4; ++mm)
#pragma unroll
      for (int nn = 0; nn < 4; ++nn) acc2[mm][nn] = (f32x4){0.f, 0.f, 0.f, 0.f};
  }

  for (int k0 = 0; k0 < K; k0 += 32) {
#pragma unroll
    for (int i = 0; i < 2; ++i) {
      const size_t rA = (size_t)(m0 + i * 64 + (t >> 2));
      gload16((const char*)A + (rA * K + k0) * 2 + (t & 3) * 16,
              (char*)As + i * 4096 + wv * 1024);
      const size_t rB = (size_t)(n0 + i * 64 + (t >> 2));
      gload16((const char*)B0 + (rB * K + k0) * 2 + (t & 3) * 16,
              (char*)Bs + i * 4096 + wv * 1024);
      if constexpr (MODE == 2)
        gload16((const char*)B1 + (rB * K + k0) * 2 + (t & 3) * 16,
                (char*)Bs2 + i * 4096 + wv * 1024);
    }
    __syncthreads();
    short8 af[4], bf0[4];
#pragma unroll
    for (int mm = 0; mm < 4; ++mm)
      af[mm] = *(const short8*)&As[(wr * 64 + mm * 16 + l15) * 32 + grp * 8];
#pragma unroll
    for (int nn = 0; nn < 4; ++nn)
      bf0[nn] = *(const short8*)&Bs[(wc * 64 + nn * 16 + l15) * 32 + grp * 8];
#pragma unroll
    for (int mm = 0; mm < 4; ++mm)
#pragma unroll
      for (int nn = 0; nn < 4; ++nn) acc[mm][nn] = MFMA(af[mm], bf0[nn], acc[mm][nn]);
    if constexpr (MODE == 2) {
      short8 bf1[4];
#pragma unroll
      for (int nn = 0; nn < 4; ++nn)
        bf1[nn] = *(const short8*)&Bs2[(wc * 64 + nn * 16 + l15) * 32 + grp * 8];
#pragma unroll
      for (int mm = 0; mm < 4; ++mm)
#pragma unroll
        for (int nn = 0; nn < 4; ++nn) acc2[mm][nn] = MFMA(af[mm], bf1[nn], acc2[mm][nn]);
    }
    __syncthreads();
  }

#pragma unroll
  for (int mm = 0; mm < 4; ++mm)
#pragma unroll
    for (int nn = 0; nn < 4; ++nn)
#pragma unroll
      for (int j = 0; j < 4; ++j) {
        const int r = m0 + wr * 64 + mm * 16 + grp * 4 + j;
        const int c = n0 + wc * 64 + nn * 16 + l15;
        float val = acc[mm][nn][j];
        if constexpr (MODE == 0) {
          const int mat = c >> 10;
          const int rem = c & 1023;
          const int hh = rem >> 6;
          const int dh = rem & 63;
          const int bt = r >> 11;
          const int lt = r & 2047;
          float outv = val;
          if (mat < 2) {  // RoPE on q,k: interleaved pairs, pos = lt
            const float partner = __shfl_xor(val, 1, 64);
            const int pr = dh >> 1;
            const float invf = __expf((float)pr * (-2.0f * 9.2103403719761836f / 64.0f));
            const float ang = (float)lt * invf;
            float sn, cs;
            sincosf(ang, &sn, &cs);
            outv = (dh & 1) ? (val * cs + partner * sn) : (val * cs - partner * sn);
          }
          unsigned short* dst = (mat == 0) ? q : ((mat == 1) ? k2 : v);
          dst[((size_t)(bt * 16 + hh) * 2048 + lt) * 64 + dh] = f2b(outv);
        } else if constexpr (MODE == 1) {
          const size_t idx = (size_t)r * N + c;
          outF[idx] = resid[idx] + val;
        } else {
          const float a1 = val, a3 = acc2[mm][nn][j];
          const float hval = a1 / (1.0f + __expf(-a1)) * a3;
          outH[(size_t)r * N + c] = f2b(hval);
        }
      }
}

// ---------------- causal flash attention, 1 wave / 16 queries ----------------
__global__ __launch_bounds__(64) void attn_k(const unsigned short* __restrict__ qb,
                                             const unsigned short* __restrict__ kb,
                                             const unsigned short* __restrict__ vb,
                                             unsigned short* __restrict__ yh) {
  const int qi = blockIdx.x;   // 0..127
  const int bh = blockIdx.y;   // 0..31
  const int lane = threadIdx.x;
  const int l15 = lane & 15, grp = lane >> 4;
  const int q0 = qi * 16;
  __shared__ __align__(16) unsigned short Pl[16 * 56];  // P tile, stride 56 (16B aligned, low bank conflict)
  __shared__ __align__(16) unsigned short VT[64 * 40];  // V^T tile, stride 40

  const unsigned short* qp = qb + ((size_t)bh * 2048 + q0) * 64;
  const short8 qf0 = *(const short8*)(qp + l15 * 64 + grp * 8);
  const short8 qf1 = *(const short8*)(qp + l15 * 64 + 32 + grp * 8);

  f32x4 o[4];
#pragma unroll
  for (int d = 0; d < 4; ++d) o[d] = (f32x4){0.f, 0.f, 0.f, 0.f};
  float mrun[4], lrun[4];
#pragma unroll
  for (int j = 0; j < 4; ++j) { mrun[j] = -__builtin_inff(); lrun[j] = 0.f; }

  const unsigned short* kbp = kb + (size_t)bh * 2048 * 64;
  const unsigned short* vbp = vb + (size_t)bh * 2048 * 64;
  const int nkt = qi / 2 + 1;

  for (int kt = 0; kt < nkt; ++kt) {
    __syncthreads();  // protect LDS from previous iteration's readers
    // stage V^T: VT[d][kk] = V[kt*32+kk][d]; lane = d
    const unsigned short* vt0 = vbp + (size_t)(kt * 32) * 64 + lane;
#pragma unroll
    for (int kk = 0; kk < 32; ++kk) VT[lane * 40 + kk] = vt0[(size_t)kk * 64];

    // S = Q K^T (two 16-col fragments)
    const unsigned short* kp = kbp + (size_t)(kt * 32) * 64;
    const short8 kf00 = *(const short8*)(kp + l15 * 64 + grp * 8);
    const short8 kf01 = *(const short8*)(kp + l15 * 64 + 32 + grp * 8);
    const short8 kf10 = *(const short8*)(kp + (16 + l15) * 64 + grp * 8);
    const short8 kf11 = *(const short8*)(kp + (16 + l15) * 64 + 32 + grp * 8);
    f32x4 s0 = {0.f, 0.f, 0.f, 0.f}, s1 = {0.f, 0.f, 0.f, 0.f};
    s0 = MFMA(qf0, kf00, s0);
    s0 = MFMA(qf1, kf01, s0);
    s1 = MFMA(qf0, kf10, s1);
    s1 = MFMA(qf1, kf11, s1);

    const int kg0 = kt * 32 + l15, kg1 = kt * 32 + 16 + l15;
    float alpha[4], p0[4], p1[4];
#pragma unroll
    for (int j = 0; j < 4; ++j) {
      const int qg = q0 + grp * 4 + j;
      float a = s0[j] * 0.125f;
      if (kg0 > qg) a = -__builtin_inff();
      float b = s1[j] * 0.125f;
      if (kg1 > qg) b = -__builtin_inff();
      float mx = fmaxf(a, b);
      mx = fmaxf(mx, __shfl_xor(mx, 1, 64));
      mx = fmaxf(mx, __shfl_xor(mx, 2, 64));
      mx = fmaxf(mx, __shfl_xor(mx, 4, 64));
      mx = fmaxf(mx, __shfl_xor(mx, 8, 64));
      const float mnew = fmaxf(mrun[j], mx);
      alpha[j] = __expf(mrun[j] - mnew);
      mrun[j] = mnew;
      const float pa = __expf(a - mnew);
      const float pb = __expf(b - mnew);
      float rs = pa + pb;
      rs += __shfl_xor(rs, 1, 64);
      rs += __shfl_xor(rs, 2, 64);
      rs += __shfl_xor(rs, 4, 64);
      rs += __shfl_xor(rs, 8, 64);
      lrun[j] = lrun[j] * alpha[j] + rs;
      p0[j] = pa;
      p1[j] = pb;
    }
#pragma unroll
    for (int d = 0; d < 4; ++d)
#pragma unroll
      for (int j = 0; j < 4; ++j) o[d][j] *= alpha[j];

    // stage P (S-layout -> row-major) for A-fragment reload
#pragma unroll
    for (int j = 0; j < 4; ++j) {
      Pl[(grp * 4 + j) * 56 + l15] = f2b(p0[j]);
      Pl[(grp * 4 + j) * 56 + 16 + l15] = f2b(p1[j]);
    }
    __syncthreads();
    const short8 pa8 = *(const short8*)&Pl[l15 * 56 + grp * 8];
#pragma unroll
    for (int d = 0; d < 4; ++d) {
      const short8 vf = *(const short8*)&VT[(d * 16 + l15) * 40 + grp * 8];
      o[d] = MFMA(pa8, vf, o[d]);
    }
  }

  const int bq = bh >> 4, hh = bh & 15;
#pragma unroll
  for (int d = 0; d < 4; ++d)
#pragma unroll
    for (int j = 0; j < 4; ++j) {
      const float valo = o[d][j] / lrun[j];
      const size_t rowo = (size_t)bq * 2048 + q0 + grp * 4 + j;
      yh[rowo * 1024 + hh * 64 + d * 16 + l15] = f2b(valo);
    }
}

extern "C" void kernel_launch(void* const* d_in, const int* in_sizes, int n_in,
                              void* d_out, int out_size, void* d_ws, size_t ws_size,
                              hipStream_t stream) {
  const float* x = (const float*)d_in[0];
  const float* wqkv = (const float*)d_in[1];
  const float* wo = (const float*)d_in[2];
  const float* w1 = (const float*)d_in[3];
  const float* w2 = (const float*)d_in[4];
  const float* w3 = (const float*)d_in[5];
  const float* g1 = (const float*)d_in[6];
  const float* g2 = (const float*)d_in[7];

  char* ws = (char*)d_ws;
  unsigned short* wqkv_b = (unsigned short*)(ws + 0);         // 3072x1024
  unsigned short* wo_b = (unsigned short*)(ws + 6291456);     // 1024x1024
  unsigned short* w1_b = (unsigned short*)(ws + 8388608);     // 4096x1024
  unsigned short* w3_b = (unsigned short*)(ws + 16777216);    // 4096x1024
  unsigned short* w2_b = (unsigned short*)(ws + 25165824);    // 1024x4096
  unsigned short* yb = (unsigned short*)(ws + 33554432);      // 4096x1024 (both norms)
  unsigned short* qb = (unsigned short*)(ws + 41943040);      // (B,H,L,DH)
  unsigned short* kb = (unsigned short*)(ws + 50331648);
  unsigned short* vb = (unsigned short*)(ws + 58720256);
  unsigned short* yh = (unsigned short*)(ws + 67108864);      // attn out (B,L,D)
  float* x2 = (float*)(ws + 75497472);                        // f32 residual
  unsigned short* hb = (unsigned short*)(ws + 41943040);      // 4096x4096, reuses q/k/v/yh
  if (ws_size < 92274688) return;

  cvt_k<<<3072, 256, 0, stream>>>(wqkv, wqkv_b, 3145728);
  cvt_k<<<1024, 256, 0, stream>>>(wo, wo_b, 1048576);
  cvt_k<<<4096, 256, 0, stream>>>(w1, w1_b, 4194304);
  cvt_k<<<4096, 256, 0, stream>>>(w3, w3_b, 4194304);
  cvt_k<<<4096, 256, 0, stream>>>(w2, w2_b, 4194304);

  rms_k<<<4096, 256, 0, stream>>>(x, g1, yb);
  gemm_bt<0><<<dim3(24, 32), 256, 0, stream>>>(yb, wqkv_b, nullptr, 4096, 3072, 1024,
                                               nullptr, nullptr, qb, kb, vb, nullptr);
  attn_k<<<dim3(128, 32), 64, 0, stream>>>(qb, kb, vb, yh);
  gemm_bt<1><<<dim3(8, 32), 256, 0, stream>>>(yh, wo_b, nullptr, 4096, 1024, 1024,
                                              x2, x, nullptr, nullptr, nullptr, nullptr);
  rms_k<<<4096, 256, 0, stream>>>(x2, g2, yb);
  gemm_bt<2><<<dim3(32, 32), 256, 0, stream>>>(yb, w1_b, w3_b, 4096, 4096, 1024,
                                               nullptr, nullptr, nullptr, nullptr, nullptr, hb);
  gemm_bt<1><<<dim3(8, 32), 256, 0, stream>>>(hb, w2_b, nullptr, 4096, 1024, 4096,
                                              (float*)d_out, x2, nullptr, nullptr, nullptr, nullptr);
}

// Round 2
// 493.915 us; speedup vs baseline: 1.0934x; 1.0934x over previous
//
#include <hip/hip_runtime.h>

// TransformerBlock on MI355X — round 1: rewritten flash attention (4-wave blocks,
// swizzled gload_lds staging, separate V-transpose), RoPE table.

typedef __attribute__((ext_vector_type(8))) short short8;
typedef __attribute__((ext_vector_type(4))) float f32x4;

#define DEV __device__ __forceinline__

DEV unsigned short f2b(float f) {
  unsigned int u = __builtin_bit_cast(unsigned int, f);
  unsigned int r = u + 0x7fffu + ((u >> 16) & 1u);
  return (unsigned short)(r >> 16);
}
DEV f32x4 MFMA(short8 a, short8 b, f32x4 c) {
  return __builtin_amdgcn_mfma_f32_16x16x32_bf16(a, b, c, 0, 0, 0);
}
DEV void gload16(const void* g, void* lds) {
  __builtin_amdgcn_global_load_lds((const __attribute__((address_space(1))) void*)g,
                                   (__attribute__((address_space(3))) void*)lds, 16, 0, 0);
}

// ---------------- f32 -> bf16 weight conversion ----------------
__global__ __launch_bounds__(256) void cvt_k(const float* __restrict__ src,
                                             unsigned short* __restrict__ dst, int n) {
  int i = (blockIdx.x * 256 + threadIdx.x) * 4;
  if (i + 3 < n) {
    float4 v = *(const float4*)(src + i);
    ushort4 o;
    o.x = f2b(v.x); o.y = f2b(v.y); o.z = f2b(v.z); o.w = f2b(v.w);
    *(ushort4*)(dst + i) = o;
  } else {
    for (int c = 0; c < 4 && i + c < n; ++c) dst[i + c] = f2b(src[i + c]);
  }
}

// ---------------- RoPE cos/sin table: tab[lt][pr] = (cos, sin) ----------------
__global__ __launch_bounds__(256) void rope_k(float2* __restrict__ tab) {
  const int i = blockIdx.x * 256 + threadIdx.x;  // 65536 = 2048*32
  const int lt = i >> 5, pr = i & 31;
  const float invf = __expf((float)pr * -0.28782313662425572f);  // theta^(-2pr/64)
  const float ang = (float)lt * invf;
  float sn, cs;
  sincosf(ang, &sn, &cs);
  tab[i] = make_float2(cs, sn);
}

// ---------------- RMSNorm: f32 in, bf16 out (rows of 1024) ----------------
__global__ __launch_bounds__(256) void rms_k(const float* __restrict__ x,
                                             const float* __restrict__ g,
                                             unsigned short* __restrict__ out) {
  const int row = blockIdx.x;
  const int t = threadIdx.x;
  const float4 v = *(const float4*)(x + (size_t)row * 1024 + t * 4);
  float ss = v.x * v.x + v.y * v.y + v.z * v.z + v.w * v.w;
#pragma unroll
  for (int m = 32; m >= 1; m >>= 1) ss += __shfl_xor(ss, m, 64);
  __shared__ float red[4];
  if ((t & 63) == 0) red[t >> 6] = ss;
  __syncthreads();
  float tot = red[0] + red[1] + red[2] + red[3];
  float inv = rsqrtf(tot * (1.0f / 1024.0f) + 1e-5f);
  ushort4 o;
  o.x = f2b(v.x * inv * g[t * 4 + 0]);
  o.y = f2b(v.y * inv * g[t * 4 + 1]);
  o.z = f2b(v.z * inv * g[t * 4 + 2]);
  o.w = f2b(v.w * inv * g[t * 4 + 3]);
  *(ushort4*)(out + (size_t)row * 1024 + t * 4) = o;
}

// ---------------- GEMM: C[M][N] = A[M][K] * B[N][K]^T, bf16 in, MFMA ----------------
// MODE 0: QKV scatter with fused RoPE (table) -> q/k/v (B,H,L,DH) bf16
// MODE 1: outF = resid + acc (f32)
// MODE 2: dual B (w1,w3): outH = bf16(silu(acc)*acc2)
template <int MODE>
__global__ __launch_bounds__(256) void gemm_bt(
    const unsigned short* __restrict__ A, const unsigned short* __restrict__ B0,
    const unsigned short* __restrict__ B1, int M, int N, int K,
    float* __restrict__ outF, const float* __restrict__ resid,
    unsigned short* __restrict__ q, unsigned short* __restrict__ k2,
    unsigned short* __restrict__ v, unsigned short* __restrict__ outH,
    const float2* __restrict__ rtab) {
  __shared__ __align__(16) unsigned short As[128 * 32];
  __shared__ __align__(16) unsigned short Bs[128 * 32];
  __shared__ __align__(16) unsigned short Bs2[(MODE == 2) ? 128 * 32 : 8];
  const int t = threadIdx.x;
  const int wv = t >> 6, ln = t & 63;
  const int l15 = ln & 15, grp = ln >> 4;
  const int wr = wv >> 1, wc = wv & 1;
  const int m0 = blockIdx.y * 128, n0 = blockIdx.x * 128;

  f32x4 acc[4][4];
  f32x4 acc2[(MODE == 2) ? 4 : 1][(MODE == 2) ? 4 : 1];
#pragma unroll
  for (int mm = 0; mm < 4; ++mm)
#pragma unroll
    for (int nn = 0; nn < 4; ++nn) acc[mm][nn] = (f32x4){0.f, 0.f, 0.f, 0.f};
  if constexpr (MODE == 2) {
#pragma unroll
    for (int mm = 0; mm < 4; ++mm)
#pragma unroll
      for (int nn = 0; nn < 4; ++nn) acc2[mm][nn] = (f32x4){0.f, 0.f, 0.f, 0.f};
  }

  for (int k0 = 0; k0 < K; k0 += 32) {
#pragma unroll
    for (int i = 0; i < 2; ++i) {
      const size_t rA = (size_t)(m0 + i * 64 + (t >> 2));
      gload16((const char*)A + (rA * K + k0) * 2 + (t & 3) * 16,
              (char*)As + i * 4096 + wv * 1024);
      const size_t rB = (size_t)(n0 + i * 64 + (t >> 2));
      gload16((const char*)B0 + (rB * K + k0) * 2 + (t & 3) * 16,
              (char*)Bs + i * 4096 + wv * 1024);
      if constexpr (MODE == 2)
        gload16((const char*)B1 + (rB * K + k0) * 2 + (t & 3) * 16,
                (char*)Bs2 + i * 4096 + wv * 1024);
    }
    __syncthreads();
    short8 af[4], bf0[4];
#pragma unroll
    for (int mm = 0; mm < 4; ++mm)
      af[mm] = *(const short8*)&As[(wr * 64 + mm * 16 + l15) * 32 + grp * 8];
#pragma unroll
    for (int nn = 0; nn < 4; ++nn)
      bf0[nn] = *(const short8*)&Bs[(wc * 64 + nn * 16 + l15) * 32 + grp * 8];
#pragma unroll
    for (int mm = 0; mm < 4; ++mm)
#pragma unroll
      for (int nn = 0; nn < 4; ++nn) acc[mm][nn] = MFMA(af[mm], bf0[nn], acc[mm][nn]);
    if constexpr (MODE == 2) {
      short8 bf1[4];
#pragma unroll
      for (int nn = 0; nn < 4; ++nn)
        bf1[nn] = *(const short8*)&Bs2[(wc * 64 + nn * 16 + l15) * 32 + grp * 8];
#pragma unroll
      for (int mm = 0; mm < 4; ++mm)
#pragma unroll
        for (int nn = 0; nn < 4; ++nn) acc2[mm][nn] = MFMA(af[mm], bf1[nn], acc2[mm][nn]);
    }
    __syncthreads();
  }

#pragma unroll
  for (int mm = 0; mm < 4; ++mm)
#pragma unroll
    for (int nn = 0; nn < 4; ++nn)
#pragma unroll
      for (int j = 0; j < 4; ++j) {
        const int r = m0 + wr * 64 + mm * 16 + grp * 4 + j;
        const int c = n0 + wc * 64 + nn * 16 + l15;
        float val = acc[mm][nn][j];
        if constexpr (MODE == 0) {
          const int mat = c >> 10;
          const int rem = c & 1023;
          const int hh = rem >> 6;
          const int dh = rem & 63;
          const int bt = r >> 11;
          const int lt = r & 2047;
          float outv = val;
          if (mat < 2) {  // RoPE on q,k via table
            const float partner = __shfl_xor(val, 1, 64);
            const float2 cs = rtab[lt * 32 + (dh >> 1)];
            outv = (dh & 1) ? (val * cs.x + partner * cs.y) : (val * cs.x - partner * cs.y);
          }
          unsigned short* dst = (mat == 0) ? q : ((mat == 1) ? k2 : v);
          dst[((size_t)(bt * 16 + hh) * 2048 + lt) * 64 + dh] = f2b(outv);
        } else if constexpr (MODE == 1) {
          const size_t idx = (size_t)r * N + c;
          outF[idx] = resid[idx] + val;
        } else {
          const float a1 = val, a3 = acc2[mm][nn][j];
          const float hval = a1 / (1.0f + __expf(-a1)) * a3;
          outH[(size_t)r * N + c] = f2b(hval);
        }
      }
}

// ---------------- V transpose: vb[bh][lt][dh] -> vt[bh][dh][lt] ----------------
__global__ __launch_bounds__(256) void vtr_k(const unsigned short* __restrict__ v,
                                             unsigned short* __restrict__ vt) {
  __shared__ __align__(16) unsigned short tile[64][72];
  const int bh = blockIdx.y;
  const int lt0 = blockIdx.x * 64;
  const int t = threadIdx.x;
  const int r = t >> 2;
  const int c0 = (t & 3) * 16;
  const unsigned short* src = v + ((size_t)bh * 2048 + lt0 + r) * 64 + c0;
  *(short8*)&tile[r][c0] = *(const short8*)src;
  *(short8*)&tile[r][c0 + 8] = *(const short8*)(src + 8);
  __syncthreads();
  unsigned short outv[16];
#pragma unroll
  for (int i = 0; i < 16; ++i) outv[i] = tile[c0 + i][r];
  unsigned short* dst = vt + ((size_t)bh * 64 + r) * 2048 + lt0 + c0;
  *(short8*)dst = *(short8*)&outv[0];
  *(short8*)(dst + 8) = *(short8*)&outv[8];
}

// ---------------- causal flash attention: 4 waves, QBLK=64, KVBLK=64 ----------------
__global__ __launch_bounds__(256) void attn_k(const unsigned short* __restrict__ qb,
                                              const unsigned short* __restrict__ kb,
                                              const unsigned short* __restrict__ vt,
                                              unsigned short* __restrict__ yh) {
  const int qblk = gridDim.x - 1 - blockIdx.x;  // longest blocks first
  const int bh = blockIdx.y;
  const int t = threadIdx.x;
  const int w = t >> 6, lane = t & 63;
  const int l15 = lane & 15, grp = lane >> 4;
  const int q0 = qblk * 64;
  const int qw = q0 + w * 16;

  __shared__ __align__(16) char Ks[8192];  // K tile [64 kk][64 d], swizzled rows of 128B
  __shared__ __align__(16) char Vs[8192];  // V^T tile [64 d][64 kk], swizzled rows of 128B
  __shared__ __align__(16) char Ps[8192];  // per-wave P [16 q][64 kk], swizzled
  char* Pw = Ps + w * 2048;

  const unsigned short* qp = qb + ((size_t)bh * 2048 + qw) * 64;
  const short8 qf0 = *(const short8*)(qp + l15 * 64 + grp * 8);
  const short8 qf1 = *(const short8*)(qp + l15 * 64 + 32 + grp * 8);

  f32x4 o[4];
#pragma unroll
  for (int d = 0; d < 4; ++d) o[d] = (f32x4){0.f, 0.f, 0.f, 0.f};
  float mrun[4], lrun[4];
#pragma unroll
  for (int j = 0; j < 4; ++j) { mrun[j] = -3.0e38f; lrun[j] = 0.f; }

  const char* kg = (const char*)kb + (size_t)bh * 262144;
  const char* vg = (const char*)vt + (size_t)bh * 262144;

  // staging: shot s covers LDS bytes lb = s*4096 + t*16; linear LDS, swizzled global src
  const int lb0 = t * 16, lb1 = 4096 + t * 16;
  const int r0 = lb0 >> 7, r1 = lb1 >> 7;
  const int sl0 = (lb0 & 0x70) ^ ((r0 & 7) << 4);
  const int sl1 = (lb1 & 0x70) ^ ((r1 & 7) << 4);
  const char* srcK0 = kg + r0 * 128 + sl0;
  const char* srcK1 = kg + r1 * 128 + sl1;
  const char* srcV0 = vg + (size_t)r0 * 4096 + sl0;
  const char* srcV1 = vg + (size_t)r1 * 4096 + sl1;
  char* ldsK0 = Ks + w * 1024;
  char* ldsK1 = Ks + 4096 + w * 1024;
  char* ldsV0 = Vs + w * 1024;
  char* ldsV1 = Vs + 4096 + w * 1024;

  const int nkt = qblk + 1;
  for (int kt = 0; kt < nkt; ++kt) {
    __syncthreads();  // previous tile fully consumed
    gload16(srcK0 + (size_t)kt * 8192, ldsK0);
    gload16(srcK1 + (size_t)kt * 8192, ldsK1);
    gload16(srcV0 + kt * 128, ldsV0);
    gload16(srcV1 + kt * 128, ldsV1);
    __syncthreads();  // staged data visible (compiler drains vmcnt)

    // QK^T: 4 col fragments x (K=64 -> 2 MFMA)
    f32x4 s[4];
#pragma unroll
    for (int c = 0; c < 4; ++c) {
      const int r = c * 16 + l15;
      const int xr = (r & 7) << 4;
      const short8 kf0 = *(const short8*)(Ks + r * 128 + ((grp * 16) ^ xr));
      const short8 kf1 = *(const short8*)(Ks + r * 128 + ((64 + grp * 16) ^ xr));
      f32x4 z = (f32x4){0.f, 0.f, 0.f, 0.f};
      z = MFMA(qf0, kf0, z);
      z = MFMA(qf1, kf1, z);
      s[c] = z;
    }

    // online softmax (rows spread over 16 lanes: shfl_xor 1,2,4,8)
    const bool diag = (kt == qblk);
    float alpha[4], p[4][4];
#pragma unroll
    for (int j = 0; j < 4; ++j) {
      const int qg = qw + grp * 4 + j;
      float a[4];
#pragma unroll
      for (int c = 0; c < 4; ++c) {
        float av = s[c][j] * 0.125f;
        if (diag && (kt * 64 + c * 16 + l15 > qg)) av = -3.0e38f;
        a[c] = av;
      }
      float mx = fmaxf(fmaxf(a[0], a[1]), fmaxf(a[2], a[3]));
      mx = fmaxf(mx, __shfl_xor(mx, 1, 64));
      mx = fmaxf(mx, __shfl_xor(mx, 2, 64));
      mx = fmaxf(mx, __shfl_xor(mx, 4, 64));
      mx = fmaxf(mx, __shfl_xor(mx, 8, 64));
      const float mnew = fmaxf(mrun[j], mx);
      alpha[j] = __expf(mrun[j] - mnew);
      mrun[j] = mnew;
      float rs = 0.f;
#pragma unroll
      for (int c = 0; c < 4; ++c) {
        const float e = __expf(a[c] - mnew);
        p[c][j] = e;
        rs += e;
      }
      rs += __shfl_xor(rs, 1, 64);
      rs += __shfl_xor(rs, 2, 64);
      rs += __shfl_xor(rs, 4, 64);
      rs += __shfl_xor(rs, 8, 64);
      lrun[j] = lrun[j] * alpha[j] + rs;
    }
#pragma unroll
    for (int d = 0; d < 4; ++d)
#pragma unroll
      for (int j = 0; j < 4; ++j) o[d][j] *= alpha[j];

    // write P (swizzled), per-wave buffer; same-wave DS pipe keeps RAW order
#pragma unroll
    for (int j = 0; j < 4; ++j) {
      const int r = grp * 4 + j;
      const int xr = (r & 7) << 4;
      char* pr = Pw + r * 128;
#pragma unroll
      for (int c = 0; c < 4; ++c)
        *(unsigned short*)(pr + (((c * 16 + l15) * 2) ^ xr)) = f2b(p[c][j]);
    }
    // PV: A = P rows, B = V^T rows (d as output col)
    const int xp = (l15 & 7) << 4;
    const short8 pa0 = *(const short8*)(Pw + l15 * 128 + ((grp * 16) ^ xp));
    const short8 pa1 = *(const short8*)(Pw + l15 * 128 + ((64 + grp * 16) ^ xp));
#pragma unroll
    for (int db = 0; db < 4; ++db) {
      const int rv = db * 16 + l15;
      const int xv = (rv & 7) << 4;
      const short8 vf0 = *(const short8*)(Vs + rv * 128 + ((grp * 16) ^ xv));
      const short8 vf1 = *(const short8*)(Vs + rv * 128 + ((64 + grp * 16) ^ xv));
      o[db] = MFMA(pa0, vf0, o[db]);
      o[db] = MFMA(pa1, vf1, o[db]);
    }
  }

  const int bq = bh >> 4, hh = bh & 15;
#pragma unroll
  for (int db = 0; db < 4; ++db)
#pragma unroll
    for (int j = 0; j < 4; ++j) {
      const float valo = o[db][j] / lrun[j];
      const size_t rowo = (size_t)bq * 2048 + qw + grp * 4 + j;
      yh[rowo * 1024 + hh * 64 + db * 16 + l15] = f2b(valo);
    }
}

extern "C" void kernel_launch(void* const* d_in, const int* in_sizes, int n_in,
                              void* d_out, int out_size, void* d_ws, size_t ws_size,
                              hipStream_t stream) {
  const float* x = (const float*)d_in[0];
  const float* wqkv = (const float*)d_in[1];
  const float* wo = (const float*)d_in[2];
  const float* w1 = (const float*)d_in[3];
  const float* w2 = (const float*)d_in[4];
  const float* w3 = (const float*)d_in[5];
  const float* g1 = (const float*)d_in[6];
  const float* g2 = (const float*)d_in[7];

  char* ws = (char*)d_ws;
  unsigned short* wqkv_b = (unsigned short*)(ws + 0);         // 3072x1024
  unsigned short* wo_b = (unsigned short*)(ws + 6291456);     // 1024x1024
  unsigned short* w1_b = (unsigned short*)(ws + 8388608);     // 4096x1024
  unsigned short* w3_b = (unsigned short*)(ws + 16777216);    // 4096x1024
  unsigned short* w2_b = (unsigned short*)(ws + 25165824);    // 1024x4096
  float* x2 = (float*)(ws + 33554432);                        // f32 residual (16MB)
  float2* rtab = (float2*)(ws + 33554432);                    // RoPE table (aliases x2; dead before wo-gemm)
  unsigned short* yb = (unsigned short*)(ws + 50331648);      // 4096x1024 (both norms)
  unsigned short* qb = (unsigned short*)(ws + 58720256);      // (B,H,L,DH)
  unsigned short* kb = (unsigned short*)(ws + 67108864);
  unsigned short* vb = (unsigned short*)(ws + 75497472);
  unsigned short* vt = (unsigned short*)(ws + 83886080);      // V^T (B,H,DH,L)
  unsigned short* yh = vb;                                    // attn out reuses dead vb
  unsigned short* hb = (unsigned short*)(ws + 58720256);      // 4096x4096, reuses q/k/v/vt
  if (ws_size < 92274688) return;

  cvt_k<<<3072, 256, 0, stream>>>(wqkv, wqkv_b, 3145728);
  cvt_k<<<1024, 256, 0, stream>>>(wo, wo_b, 1048576);
  cvt_k<<<4096, 256, 0, stream>>>(w1, w1_b, 4194304);
  cvt_k<<<4096, 256, 0, stream>>>(w3, w3_b, 4194304);
  cvt_k<<<4096, 256, 0, stream>>>(w2, w2_b, 4194304);
  rope_k<<<256, 256, 0, stream>>>(rtab);

  rms_k<<<4096, 256, 0, stream>>>(x, g1, yb);
  gemm_bt<0><<<dim3(24, 32), 256, 0, stream>>>(yb, wqkv_b, nullptr, 4096, 3072, 1024,
                                               nullptr, nullptr, qb, kb, vb, nullptr, rtab);
  vtr_k<<<dim3(32, 32), 256, 0, stream>>>(vb, vt);
  attn_k<<<dim3(32, 32), 256, 0, stream>>>(qb, kb, vt, yh);
  gemm_bt<1><<<dim3(8, 32), 256, 0, stream>>>(yh, wo_b, nullptr, 4096, 1024, 1024,
                                              x2, x, nullptr, nullptr, nullptr, nullptr, nullptr);
  rms_k<<<4096, 256, 0, stream>>>(x2, g2, yb);
  gemm_bt<2><<<dim3(32, 32), 256, 0, stream>>>(yb, w1_b, w3_b, 4096, 4096, 1024,
                                               nullptr, nullptr, nullptr, nullptr, nullptr, hb, nullptr);
  gemm_bt<1><<<dim3(8, 32), 256, 0, stream>>>(hb, w2_b, nullptr, 4096, 1024, 4096,
                                              (float*)d_out, x2, nullptr, nullptr, nullptr, nullptr, nullptr);
}

// Round 3
// 399.919 us; speedup vs baseline: 1.3504x; 1.2350x over previous
//
#include <hip/hip_runtime.h>

// TransformerBlock on MI355X — round 2: FFN dual-GEMM folded into N-dim
// (interleaved w1/w3 16-row groups) to cut 128 accumulator AGPRs -> 64,
// recovering occupancy; __launch_bounds__(256,3) on all GEMMs.

typedef __attribute__((ext_vector_type(8))) short short8;
typedef __attribute__((ext_vector_type(4))) float f32x4;

#define DEV __device__ __forceinline__

DEV unsigned short f2b(float f) {
  unsigned int u = __builtin_bit_cast(unsigned int, f);
  unsigned int r = u + 0x7fffu + ((u >> 16) & 1u);
  return (unsigned short)(r >> 16);
}
DEV f32x4 MFMA(short8 a, short8 b, f32x4 c) {
  return __builtin_amdgcn_mfma_f32_16x16x32_bf16(a, b, c, 0, 0, 0);
}
DEV void gload16(const void* g, void* lds) {
  __builtin_amdgcn_global_load_lds((const __attribute__((address_space(1))) void*)g,
                                   (__attribute__((address_space(3))) void*)lds, 16, 0, 0);
}

// ---------------- f32 -> bf16 weight conversion ----------------
__global__ __launch_bounds__(256) void cvt_k(const float* __restrict__ src,
                                             unsigned short* __restrict__ dst, int n) {
  int i = (blockIdx.x * 256 + threadIdx.x) * 4;
  if (i + 3 < n) {
    float4 v = *(const float4*)(src + i);
    ushort4 o;
    o.x = f2b(v.x); o.y = f2b(v.y); o.z = f2b(v.z); o.w = f2b(v.w);
    *(ushort4*)(dst + i) = o;
  } else {
    for (int c = 0; c < 4 && i + c < n; ++c) dst[i + c] = f2b(src[i + c]);
  }
}

// ---------------- RoPE cos/sin table: tab[lt][pr] = (cos, sin) ----------------
__global__ __launch_bounds__(256) void rope_k(float2* __restrict__ tab) {
  const int i = blockIdx.x * 256 + threadIdx.x;  // 65536 = 2048*32
  const int lt = i >> 5, pr = i & 31;
  const float invf = __expf((float)pr * -0.28782313662425572f);  // theta^(-2pr/64)
  const float ang = (float)lt * invf;
  float sn, cs;
  sincosf(ang, &sn, &cs);
  tab[i] = make_float2(cs, sn);
}

// ---------------- RMSNorm: f32 in, bf16 out (rows of 1024) ----------------
__global__ __launch_bounds__(256) void rms_k(const float* __restrict__ x,
                                             const float* __restrict__ g,
                                             unsigned short* __restrict__ out) {
  const int row = blockIdx.x;
  const int t = threadIdx.x;
  const float4 v = *(const float4*)(x + (size_t)row * 1024 + t * 4);
  float ss = v.x * v.x + v.y * v.y + v.z * v.z + v.w * v.w;
#pragma unroll
  for (int m = 32; m >= 1; m >>= 1) ss += __shfl_xor(ss, m, 64);
  __shared__ float red[4];
  if ((t & 63) == 0) red[t >> 6] = ss;
  __syncthreads();
  float tot = red[0] + red[1] + red[2] + red[3];
  float inv = rsqrtf(tot * (1.0f / 1024.0f) + 1e-5f);
  ushort4 o;
  o.x = f2b(v.x * inv * g[t * 4 + 0]);
  o.y = f2b(v.y * inv * g[t * 4 + 1]);
  o.z = f2b(v.z * inv * g[t * 4 + 2]);
  o.w = f2b(v.w * inv * g[t * 4 + 3]);
  *(ushort4*)(out + (size_t)row * 1024 + t * 4) = o;
}

// ---------------- GEMM: C[M][N] = A[M][K] * B[N][K]^T, bf16 in, MFMA ----------------
// MODE 0: QKV scatter with fused RoPE (table) -> q/k/v (B,H,L,DH) bf16; tile 128x128
// MODE 1: outF = resid + acc (f32); tile 128x128
// MODE 2: dual B interleaved in N (even 16-group = w1, odd = w3, same channels):
//         tile 128 rows x 64 channels; outH = bf16(silu(h1)*h3)
template <int MODE>
__global__ __launch_bounds__(256, 3) void gemm_bt(
    const unsigned short* __restrict__ A, const unsigned short* __restrict__ B0,
    const unsigned short* __restrict__ B1, int M, int N, int K,
    float* __restrict__ outF, const float* __restrict__ resid,
    unsigned short* __restrict__ q, unsigned short* __restrict__ k2,
    unsigned short* __restrict__ v, unsigned short* __restrict__ outH,
    const float2* __restrict__ rtab) {
  __shared__ __align__(16) unsigned short As[128 * 32];
  __shared__ __align__(16) unsigned short Bs[128 * 32];
  const int t = threadIdx.x;
  const int wv = t >> 6, ln = t & 63;
  const int l15 = ln & 15, grp = ln >> 4;
  const int wr = wv >> 1, wc = wv & 1;
  const int m0 = blockIdx.y * 128;
  const int n0 = blockIdx.x * ((MODE == 2) ? 64 : 128);

  f32x4 acc[4][4];
#pragma unroll
  for (int mm = 0; mm < 4; ++mm)
#pragma unroll
    for (int nn = 0; nn < 4; ++nn) acc[mm][nn] = (f32x4){0.f, 0.f, 0.f, 0.f};

  for (int k0 = 0; k0 < K; k0 += 32) {
#pragma unroll
    for (int i = 0; i < 2; ++i) {
      const size_t rA = (size_t)(m0 + i * 64 + (t >> 2));
      gload16((const char*)A + (rA * K + k0) * 2 + (t & 3) * 16,
              (char*)As + i * 4096 + wv * 1024);
      const int rr = i * 64 + (t >> 2);
      const unsigned short* bsrc;
      int brow;
      if constexpr (MODE == 2) {
        const int g = rr >> 4;
        bsrc = (g & 1) ? B1 : B0;
        brow = n0 + ((g >> 1) << 4) + (rr & 15);
      } else {
        bsrc = B0;
        brow = n0 + rr;
      }
      gload16((const char*)bsrc + ((size_t)brow * K + k0) * 2 + (t & 3) * 16,
              (char*)Bs + i * 4096 + wv * 1024);
    }
    __syncthreads();
    short8 af[4], bf0[4];
#pragma unroll
    for (int mm = 0; mm < 4; ++mm)
      af[mm] = *(const short8*)&As[(wr * 64 + mm * 16 + l15) * 32 + grp * 8];
#pragma unroll
    for (int nn = 0; nn < 4; ++nn)
      bf0[nn] = *(const short8*)&Bs[(wc * 64 + nn * 16 + l15) * 32 + grp * 8];
#pragma unroll
    for (int mm = 0; mm < 4; ++mm)
#pragma unroll
      for (int nn = 0; nn < 4; ++nn) acc[mm][nn] = MFMA(af[mm], bf0[nn], acc[mm][nn]);
    __syncthreads();
  }

  if constexpr (MODE == 2) {
#pragma unroll
    for (int mm = 0; mm < 4; ++mm)
#pragma unroll
      for (int np = 0; np < 2; ++np)
#pragma unroll
        for (int j = 0; j < 4; ++j) {
          const int r = m0 + wr * 64 + mm * 16 + grp * 4 + j;
          const int c = n0 + (2 * wc + np) * 16 + l15;
          const float a1 = acc[mm][2 * np][j];
          const float a3 = acc[mm][2 * np + 1][j];
          const float hval = a1 / (1.0f + __expf(-a1)) * a3;
          outH[(size_t)r * N + c] = f2b(hval);
        }
  } else {
#pragma unroll
    for (int mm = 0; mm < 4; ++mm)
#pragma unroll
      for (int nn = 0; nn < 4; ++nn)
#pragma unroll
        for (int j = 0; j < 4; ++j) {
          const int r = m0 + wr * 64 + mm * 16 + grp * 4 + j;
          const int c = n0 + wc * 64 + nn * 16 + l15;
          float val = acc[mm][nn][j];
          if constexpr (MODE == 0) {
            const int mat = c >> 10;
            const int rem = c & 1023;
            const int hh = rem >> 6;
            const int dh = rem & 63;
            const int bt = r >> 11;
            const int lt = r & 2047;
            float outv = val;
            if (mat < 2) {  // RoPE on q,k via table
              const float partner = __shfl_xor(val, 1, 64);
              const float2 cs = rtab[lt * 32 + (dh >> 1)];
              outv = (dh & 1) ? (val * cs.x + partner * cs.y) : (val * cs.x - partner * cs.y);
            }
            unsigned short* dst = (mat == 0) ? q : ((mat == 1) ? k2 : v);
            dst[((size_t)(bt * 16 + hh) * 2048 + lt) * 64 + dh] = f2b(outv);
          } else {
            const size_t idx = (size_t)r * N + c;
            outF[idx] = resid[idx] + val;
          }
        }
  }
}

// ---------------- V transpose: vb[bh][lt][dh] -> vt[bh][dh][lt] ----------------
__global__ __launch_bounds__(256) void vtr_k(const unsigned short* __restrict__ v,
                                             unsigned short* __restrict__ vt) {
  __shared__ __align__(16) unsigned short tile[64][72];
  const int bh = blockIdx.y;
  const int lt0 = blockIdx.x * 64;
  const int t = threadIdx.x;
  const int r = t >> 2;
  const int c0 = (t & 3) * 16;
  const unsigned short* src = v + ((size_t)bh * 2048 + lt0 + r) * 64 + c0;
  *(short8*)&tile[r][c0] = *(const short8*)src;
  *(short8*)&tile[r][c0 + 8] = *(const short8*)(src + 8);
  __syncthreads();
  unsigned short outv[16];
#pragma unroll
  for (int i = 0; i < 16; ++i) outv[i] = tile[c0 + i][r];
  unsigned short* dst = vt + ((size_t)bh * 64 + r) * 2048 + lt0 + c0;
  *(short8*)dst = *(short8*)&outv[0];
  *(short8*)(dst + 8) = *(short8*)&outv[8];
}

// ---------------- causal flash attention: 4 waves, QBLK=64, KVBLK=64 ----------------
__global__ __launch_bounds__(256) void attn_k(const unsigned short* __restrict__ qb,
                                              const unsigned short* __restrict__ kb,
                                              const unsigned short* __restrict__ vt,
                                              unsigned short* __restrict__ yh) {
  const int qblk = gridDim.x - 1 - blockIdx.x;  // longest blocks first
  const int bh = blockIdx.y;
  const int t = threadIdx.x;
  const int w = t >> 6, lane = t & 63;
  const int l15 = lane & 15, grp = lane >> 4;
  const int q0 = qblk * 64;
  const int qw = q0 + w * 16;

  __shared__ __align__(16) char Ks[8192];  // K tile [64 kk][64 d], swizzled rows of 128B
  __shared__ __align__(16) char Vs[8192];  // V^T tile [64 d][64 kk], swizzled rows of 128B
  __shared__ __align__(16) char Ps[8192];  // per-wave P [16 q][64 kk], swizzled
  char* Pw = Ps + w * 2048;

  const unsigned short* qp = qb + ((size_t)bh * 2048 + qw) * 64;
  const short8 qf0 = *(const short8*)(qp + l15 * 64 + grp * 8);
  const short8 qf1 = *(const short8*)(qp + l15 * 64 + 32 + grp * 8);

  f32x4 o[4];
#pragma unroll
  for (int d = 0; d < 4; ++d) o[d] = (f32x4){0.f, 0.f, 0.f, 0.f};
  float mrun[4], lrun[4];
#pragma unroll
  for (int j = 0; j < 4; ++j) { mrun[j] = -3.0e38f; lrun[j] = 0.f; }

  const char* kg = (const char*)kb + (size_t)bh * 262144;
  const char* vg = (const char*)vt + (size_t)bh * 262144;

  // staging: shot s covers LDS bytes lb = s*4096 + t*16; linear LDS, swizzled global src
  const int lb0 = t * 16, lb1 = 4096 + t * 16;
  const int r0 = lb0 >> 7, r1 = lb1 >> 7;
  const int sl0 = (lb0 & 0x70) ^ ((r0 & 7) << 4);
  const int sl1 = (lb1 & 0x70) ^ ((r1 & 7) << 4);
  const char* srcK0 = kg + r0 * 128 + sl0;
  const char* srcK1 = kg + r1 * 128 + sl1;
  const char* srcV0 = vg + (size_t)r0 * 4096 + sl0;
  const char* srcV1 = vg + (size_t)r1 * 4096 + sl1;
  char* ldsK0 = Ks + w * 1024;
  char* ldsK1 = Ks + 4096 + w * 1024;
  char* ldsV0 = Vs + w * 1024;
  char* ldsV1 = Vs + 4096 + w * 1024;

  const int nkt = qblk + 1;
  for (int kt = 0; kt < nkt; ++kt) {
    __syncthreads();  // previous tile fully consumed
    gload16(srcK0 + (size_t)kt * 8192, ldsK0);
    gload16(srcK1 + (size_t)kt * 8192, ldsK1);
    gload16(srcV0 + kt * 128, ldsV0);
    gload16(srcV1 + kt * 128, ldsV1);
    __syncthreads();  // staged data visible (compiler drains vmcnt)

    // QK^T: 4 col fragments x (K=64 -> 2 MFMA)
    f32x4 s[4];
#pragma unroll
    for (int c = 0; c < 4; ++c) {
      const int r = c * 16 + l15;
      const int xr = (r & 7) << 4;
      const short8 kf0 = *(const short8*)(Ks + r * 128 + ((grp * 16) ^ xr));
      const short8 kf1 = *(const short8*)(Ks + r * 128 + ((64 + grp * 16) ^ xr));
      f32x4 z = (f32x4){0.f, 0.f, 0.f, 0.f};
      z = MFMA(qf0, kf0, z);
      z = MFMA(qf1, kf1, z);
      s[c] = z;
    }

    // online softmax (rows spread over 16 lanes: shfl_xor 1,2,4,8)
    const bool diag = (kt == qblk);
    float alpha[4], p[4][4];
#pragma unroll
    for (int j = 0; j < 4; ++j) {
      const int qg = qw + grp * 4 + j;
      float a[4];
#pragma unroll
      for (int c = 0; c < 4; ++c) {
        float av = s[c][j] * 0.125f;
        if (diag && (kt * 64 + c * 16 + l15 > qg)) av = -3.0e38f;
        a[c] = av;
      }
      float mx = fmaxf(fmaxf(a[0], a[1]), fmaxf(a[2], a[3]));
      mx = fmaxf(mx, __shfl_xor(mx, 1, 64));
      mx = fmaxf(mx, __shfl_xor(mx, 2, 64));
      mx = fmaxf(mx, __shfl_xor(mx, 4, 64));
      mx = fmaxf(mx, __shfl_xor(mx, 8, 64));
      const float mnew = fmaxf(mrun[j], mx);
      alpha[j] = __expf(mrun[j] - mnew);
      mrun[j] = mnew;
      float rs = 0.f;
#pragma unroll
      for (int c = 0; c < 4; ++c) {
        const float e = __expf(a[c] - mnew);
        p[c][j] = e;
        rs += e;
      }
      rs += __shfl_xor(rs, 1, 64);
      rs += __shfl_xor(rs, 2, 64);
      rs += __shfl_xor(rs, 4, 64);
      rs += __shfl_xor(rs, 8, 64);
      lrun[j] = lrun[j] * alpha[j] + rs;
    }
#pragma unroll
    for (int d = 0; d < 4; ++d)
#pragma unroll
      for (int j = 0; j < 4; ++j) o[d][j] *= alpha[j];

    // write P (swizzled), per-wave buffer; same-wave DS pipe keeps RAW order
#pragma unroll
    for (int j = 0; j < 4; ++j) {
      const int r = grp * 4 + j;
      const int xr = (r & 7) << 4;
      char* pr = Pw + r * 128;
#pragma unroll
      for (int c = 0; c < 4; ++c)
        *(unsigned short*)(pr + (((c * 16 + l15) * 2) ^ xr)) = f2b(p[c][j]);
    }
    // PV: A = P rows, B = V^T rows (d as output col)
    const int xp = (l15 & 7) << 4;
    const short8 pa0 = *(const short8*)(Pw + l15 * 128 + ((grp * 16) ^ xp));
    const short8 pa1 = *(const short8*)(Pw + l15 * 128 + ((64 + grp * 16) ^ xp));
#pragma unroll
    for (int db = 0; db < 4; ++db) {
      const int rv = db * 16 + l15;
      const int xv = (rv & 7) << 4;
      const short8 vf0 = *(const short8*)(Vs + rv * 128 + ((grp * 16) ^ xv));
      const short8 vf1 = *(const short8*)(Vs + rv * 128 + ((64 + grp * 16) ^ xv));
      o[db] = MFMA(pa0, vf0, o[db]);
      o[db] = MFMA(pa1, vf1, o[db]);
    }
  }

  const int bq = bh >> 4, hh = bh & 15;
#pragma unroll
  for (int db = 0; db < 4; ++db)
#pragma unroll
    for (int j = 0; j < 4; ++j) {
      const float valo = o[db][j] / lrun[j];
      const size_t rowo = (size_t)bq * 2048 + qw + grp * 4 + j;
      yh[rowo * 1024 + hh * 64 + db * 16 + l15] = f2b(valo);
    }
}

extern "C" void kernel_launch(void* const* d_in, const int* in_sizes, int n_in,
                              void* d_out, int out_size, void* d_ws, size_t ws_size,
                              hipStream_t stream) {
  const float* x = (const float*)d_in[0];
  const float* wqkv = (const float*)d_in[1];
  const float* wo = (const float*)d_in[2];
  const float* w1 = (const float*)d_in[3];
  const float* w2 = (const float*)d_in[4];
  const float* w3 = (const float*)d_in[5];
  const float* g1 = (const float*)d_in[6];
  const float* g2 = (const float*)d_in[7];

  char* ws = (char*)d_ws;
  unsigned short* wqkv_b = (unsigned short*)(ws + 0);         // 3072x1024
  unsigned short* wo_b = (unsigned short*)(ws + 6291456);     // 1024x1024
  unsigned short* w1_b = (unsigned short*)(ws + 8388608);     // 4096x1024
  unsigned short* w3_b = (unsigned short*)(ws + 16777216);    // 4096x1024
  unsigned short* w2_b = (unsigned short*)(ws + 25165824);    // 1024x4096
  float* x2 = (float*)(ws + 33554432);                        // f32 residual (16MB)
  float2* rtab = (float2*)(ws + 33554432);                    // RoPE table (aliases x2; dead before wo-gemm)
  unsigned short* yb = (unsigned short*)(ws + 50331648);      // 4096x1024 (both norms)
  unsigned short* qb = (unsigned short*)(ws + 58720256);      // (B,H,L,DH)
  unsigned short* kb = (unsigned short*)(ws + 67108864);
  unsigned short* vb = (unsigned short*)(ws + 75497472);
  unsigned short* vt = (unsigned short*)(ws + 83886080);      // V^T (B,H,DH,L)
  unsigned short* yh = vb;                                    // attn out reuses dead vb
  unsigned short* hb = (unsigned short*)(ws + 58720256);      // 4096x4096, reuses q/k/v/vt
  if (ws_size < 92274688) return;

  cvt_k<<<3072, 256, 0, stream>>>(wqkv, wqkv_b, 3145728);
  cvt_k<<<1024, 256, 0, stream>>>(wo, wo_b, 1048576);
  cvt_k<<<4096, 256, 0, stream>>>(w1, w1_b, 4194304);
  cvt_k<<<4096, 256, 0, stream>>>(w3, w3_b, 4194304);
  cvt_k<<<4096, 256, 0, stream>>>(w2, w2_b, 4194304);
  rope_k<<<256, 256, 0, stream>>>(rtab);

  rms_k<<<4096, 256, 0, stream>>>(x, g1, yb);
  gemm_bt<0><<<dim3(24, 32), 256, 0, stream>>>(yb, wqkv_b, nullptr, 4096, 3072, 1024,
                                               nullptr, nullptr, qb, kb, vb, nullptr, rtab);
  vtr_k<<<dim3(32, 32), 256, 0, stream>>>(vb, vt);
  attn_k<<<dim3(32, 32), 256, 0, stream>>>(qb, kb, vt, yh);
  gemm_bt<1><<<dim3(8, 32), 256, 0, stream>>>(yh, wo_b, nullptr, 4096, 1024, 1024,
                                              x2, x, nullptr, nullptr, nullptr, nullptr, nullptr);
  rms_k<<<4096, 256, 0, stream>>>(x2, g2, yb);
  gemm_bt<2><<<dim3(64, 32), 256, 0, stream>>>(yb, w1_b, w3_b, 4096, 4096, 1024,
                                               nullptr, nullptr, nullptr, nullptr, nullptr, hb, nullptr);
  gemm_bt<1><<<dim3(8, 32), 256, 0, stream>>>(hb, w2_b, nullptr, 4096, 1024, 4096,
                                              (float*)d_out, x2, nullptr, nullptr, nullptr, nullptr, nullptr);
}

// Round 4
// 341.964 us; speedup vs baseline: 1.5792x; 1.1695x over previous
//
#include <hip/hip_runtime.h>

// TransformerBlock on MI355X — round 3: attention rebuilt with complementary
// q-tile pairing (perfect load balance: 33 tile-units/block) and a 2-phase
// double-buffered prefetch pipeline (counted vmcnt(4) + raw s_barrier).

typedef __attribute__((ext_vector_type(8))) short short8;
typedef __attribute__((ext_vector_type(4))) float f32x4;

#define DEV __device__ __forceinline__

DEV unsigned short f2b(float f) {
  unsigned int u = __builtin_bit_cast(unsigned int, f);
  unsigned int r = u + 0x7fffu + ((u >> 16) & 1u);
  return (unsigned short)(r >> 16);
}
DEV f32x4 MFMA(short8 a, short8 b, f32x4 c) {
  return __builtin_amdgcn_mfma_f32_16x16x32_bf16(a, b, c, 0, 0, 0);
}
DEV void gload16(const void* g, void* lds) {
  __builtin_amdgcn_global_load_lds((const __attribute__((address_space(1))) void*)g,
                                   (__attribute__((address_space(3))) void*)lds, 16, 0, 0);
}

// ---------------- f32 -> bf16 weight conversion ----------------
__global__ __launch_bounds__(256) void cvt_k(const float* __restrict__ src,
                                             unsigned short* __restrict__ dst, int n) {
  int i = (blockIdx.x * 256 + threadIdx.x) * 4;
  if (i + 3 < n) {
    float4 v = *(const float4*)(src + i);
    ushort4 o;
    o.x = f2b(v.x); o.y = f2b(v.y); o.z = f2b(v.z); o.w = f2b(v.w);
    *(ushort4*)(dst + i) = o;
  } else {
    for (int c = 0; c < 4 && i + c < n; ++c) dst[i + c] = f2b(src[i + c]);
  }
}

// ---------------- RoPE cos/sin table: tab[lt][pr] = (cos, sin) ----------------
__global__ __launch_bounds__(256) void rope_k(float2* __restrict__ tab) {
  const int i = blockIdx.x * 256 + threadIdx.x;  // 65536 = 2048*32
  const int lt = i >> 5, pr = i & 31;
  const float invf = __expf((float)pr * -0.28782313662425572f);  // theta^(-2pr/64)
  const float ang = (float)lt * invf;
  float sn, cs;
  sincosf(ang, &sn, &cs);
  tab[i] = make_float2(cs, sn);
}

// ---------------- RMSNorm: f32 in, bf16 out (rows of 1024) ----------------
__global__ __launch_bounds__(256) void rms_k(const float* __restrict__ x,
                                             const float* __restrict__ g,
                                             unsigned short* __restrict__ out) {
  const int row = blockIdx.x;
  const int t = threadIdx.x;
  const float4 v = *(const float4*)(x + (size_t)row * 1024 + t * 4);
  float ss = v.x * v.x + v.y * v.y + v.z * v.z + v.w * v.w;
#pragma unroll
  for (int m = 32; m >= 1; m >>= 1) ss += __shfl_xor(ss, m, 64);
  __shared__ float red[4];
  if ((t & 63) == 0) red[t >> 6] = ss;
  __syncthreads();
  float tot = red[0] + red[1] + red[2] + red[3];
  float inv = rsqrtf(tot * (1.0f / 1024.0f) + 1e-5f);
  ushort4 o;
  o.x = f2b(v.x * inv * g[t * 4 + 0]);
  o.y = f2b(v.y * inv * g[t * 4 + 1]);
  o.z = f2b(v.z * inv * g[t * 4 + 2]);
  o.w = f2b(v.w * inv * g[t * 4 + 3]);
  *(ushort4*)(out + (size_t)row * 1024 + t * 4) = o;
}

// ---------------- GEMM: C[M][N] = A[M][K] * B[N][K]^T, bf16 in, MFMA ----------------
// MODE 0: QKV scatter with fused RoPE (table) -> q/k/v (B,H,L,DH) bf16; tile 128x128
// MODE 1: outF = resid + acc (f32); tile 128x128
// MODE 2: dual B interleaved in N (even 16-group = w1, odd = w3, same channels):
//         tile 128 rows x 64 channels; outH = bf16(silu(h1)*h3)
template <int MODE>
__global__ __launch_bounds__(256, 3) void gemm_bt(
    const unsigned short* __restrict__ A, const unsigned short* __restrict__ B0,
    const unsigned short* __restrict__ B1, int M, int N, int K,
    float* __restrict__ outF, const float* __restrict__ resid,
    unsigned short* __restrict__ q, unsigned short* __restrict__ k2,
    unsigned short* __restrict__ v, unsigned short* __restrict__ outH,
    const float2* __restrict__ rtab) {
  __shared__ __align__(16) unsigned short As[128 * 32];
  __shared__ __align__(16) unsigned short Bs[128 * 32];
  const int t = threadIdx.x;
  const int wv = t >> 6, ln = t & 63;
  const int l15 = ln & 15, grp = ln >> 4;
  const int wr = wv >> 1, wc = wv & 1;
  const int m0 = blockIdx.y * 128;
  const int n0 = blockIdx.x * ((MODE == 2) ? 64 : 128);

  f32x4 acc[4][4];
#pragma unroll
  for (int mm = 0; mm < 4; ++mm)
#pragma unroll
    for (int nn = 0; nn < 4; ++nn) acc[mm][nn] = (f32x4){0.f, 0.f, 0.f, 0.f};

  for (int k0 = 0; k0 < K; k0 += 32) {
#pragma unroll
    for (int i = 0; i < 2; ++i) {
      const size_t rA = (size_t)(m0 + i * 64 + (t >> 2));
      gload16((const char*)A + (rA * K + k0) * 2 + (t & 3) * 16,
              (char*)As + i * 4096 + wv * 1024);
      const int rr = i * 64 + (t >> 2);
      const unsigned short* bsrc;
      int brow;
      if constexpr (MODE == 2) {
        const int g = rr >> 4;
        bsrc = (g & 1) ? B1 : B0;
        brow = n0 + ((g >> 1) << 4) + (rr & 15);
      } else {
        bsrc = B0;
        brow = n0 + rr;
      }
      gload16((const char*)bsrc + ((size_t)brow * K + k0) * 2 + (t & 3) * 16,
              (char*)Bs + i * 4096 + wv * 1024);
    }
    __syncthreads();
    short8 af[4], bf0[4];
#pragma unroll
    for (int mm = 0; mm < 4; ++mm)
      af[mm] = *(const short8*)&As[(wr * 64 + mm * 16 + l15) * 32 + grp * 8];
#pragma unroll
    for (int nn = 0; nn < 4; ++nn)
      bf0[nn] = *(const short8*)&Bs[(wc * 64 + nn * 16 + l15) * 32 + grp * 8];
#pragma unroll
    for (int mm = 0; mm < 4; ++mm)
#pragma unroll
      for (int nn = 0; nn < 4; ++nn) acc[mm][nn] = MFMA(af[mm], bf0[nn], acc[mm][nn]);
    __syncthreads();
  }

  if constexpr (MODE == 2) {
#pragma unroll
    for (int mm = 0; mm < 4; ++mm)
#pragma unroll
      for (int np = 0; np < 2; ++np)
#pragma unroll
        for (int j = 0; j < 4; ++j) {
          const int r = m0 + wr * 64 + mm * 16 + grp * 4 + j;
          const int c = n0 + (2 * wc + np) * 16 + l15;
          const float a1 = acc[mm][2 * np][j];
          const float a3 = acc[mm][2 * np + 1][j];
          const float hval = a1 / (1.0f + __expf(-a1)) * a3;
          outH[(size_t)r * N + c] = f2b(hval);
        }
  } else {
#pragma unroll
    for (int mm = 0; mm < 4; ++mm)
#pragma unroll
      for (int nn = 0; nn < 4; ++nn)
#pragma unroll
        for (int j = 0; j < 4; ++j) {
          const int r = m0 + wr * 64 + mm * 16 + grp * 4 + j;
          const int c = n0 + wc * 64 + nn * 16 + l15;
          float val = acc[mm][nn][j];
          if constexpr (MODE == 0) {
            const int mat = c >> 10;
            const int rem = c & 1023;
            const int hh = rem >> 6;
            const int dh = rem & 63;
            const int bt = r >> 11;
            const int lt = r & 2047;
            float outv = val;
            if (mat < 2) {  // RoPE on q,k via table
              const float partner = __shfl_xor(val, 1, 64);
              const float2 cs = rtab[lt * 32 + (dh >> 1)];
              outv = (dh & 1) ? (val * cs.x + partner * cs.y) : (val * cs.x - partner * cs.y);
            }
            unsigned short* dst = (mat == 0) ? q : ((mat == 1) ? k2 : v);
            dst[((size_t)(bt * 16 + hh) * 2048 + lt) * 64 + dh] = f2b(outv);
          } else {
            const size_t idx = (size_t)r * N + c;
            outF[idx] = resid[idx] + val;
          }
        }
  }
}

// ---------------- V transpose: vb[bh][lt][dh] -> vt[bh][dh][lt] ----------------
__global__ __launch_bounds__(256) void vtr_k(const unsigned short* __restrict__ v,
                                             unsigned short* __restrict__ vt) {
  __shared__ __align__(16) unsigned short tile[64][72];
  const int bh = blockIdx.y;
  const int lt0 = blockIdx.x * 64;
  const int t = threadIdx.x;
  const int r = t >> 2;
  const int c0 = (t & 3) * 16;
  const unsigned short* src = v + ((size_t)bh * 2048 + lt0 + r) * 64 + c0;
  *(short8*)&tile[r][c0] = *(const short8*)src;
  *(short8*)&tile[r][c0 + 8] = *(const short8*)(src + 8);
  __syncthreads();
  unsigned short outv[16];
#pragma unroll
  for (int i = 0; i < 16; ++i) outv[i] = tile[c0 + i][r];
  unsigned short* dst = vt + ((size_t)bh * 64 + r) * 2048 + lt0 + c0;
  *(short8*)dst = *(short8*)&outv[0];
  *(short8*)(dst + 8) = *(short8*)&outv[8];
}

// ---------------- causal flash attention: 4 waves, QBLK=64, KVBLK=64 ----------------
// Each block runs two complementary q-tiles (31-pair, then pair): 33 tile-units
// per block. Per-half: double-buffered K/V prefetch, counted vmcnt(4), raw barriers.
__global__ __launch_bounds__(256) void attn_k(const unsigned short* __restrict__ qb,
                                              const unsigned short* __restrict__ kb,
                                              const unsigned short* __restrict__ vt,
                                              unsigned short* __restrict__ yh) {
  const int pair = blockIdx.x;  // 0..15
  const int bh = blockIdx.y;
  const int t = threadIdx.x;
  const int w = t >> 6, lane = t & 63;
  const int l15 = lane & 15, grp = lane >> 4;

  __shared__ __align__(16) char Ks[2][8192];  // K tile [64 kk][64 d], swizzled rows of 128B
  __shared__ __align__(16) char Vs[2][8192];  // V^T tile [64 d][64 kk], swizzled rows of 128B
  __shared__ __align__(16) char Ps[8192];     // per-wave P [16 q][64 kk], swizzled
  char* Pw = Ps + w * 2048;

  const char* kg = (const char*)kb + (size_t)bh * 262144;
  const char* vg = (const char*)vt + (size_t)bh * 262144;

  // staging: shot s covers LDS bytes lb = s*4096 + t*16; linear LDS, swizzled global src
  const int lb0 = t * 16, lb1 = 4096 + t * 16;
  const int r0 = lb0 >> 7, r1 = lb1 >> 7;
  const int sl0 = (lb0 & 0x70) ^ ((r0 & 7) << 4);
  const int sl1 = (lb1 & 0x70) ^ ((r1 & 7) << 4);
  const char* srcK0 = kg + r0 * 128 + sl0;
  const char* srcK1 = kg + r1 * 128 + sl1;
  const char* srcV0 = vg + (size_t)r0 * 4096 + sl0;
  const char* srcV1 = vg + (size_t)r1 * 4096 + sl1;

  const int bq = bh >> 4, hh = bh & 15;

#pragma unroll 1
  for (int half = 0; half < 2; ++half) {
    const int qblk = half ? pair : (31 - pair);
    const int qw = qblk * 64 + w * 16;

    const unsigned short* qp = qb + ((size_t)bh * 2048 + qw) * 64;
    const short8 qf0 = *(const short8*)(qp + l15 * 64 + grp * 8);
    const short8 qf1 = *(const short8*)(qp + l15 * 64 + 32 + grp * 8);

    f32x4 o[4];
#pragma unroll
    for (int d = 0; d < 4; ++d) o[d] = (f32x4){0.f, 0.f, 0.f, 0.f};
    float mrun[4], lrun[4];
#pragma unroll
    for (int j = 0; j < 4; ++j) { mrun[j] = -3.0e38f; lrun[j] = 0.f; }

    const int nkt = qblk + 1;

    // full drain: previous half's reads/in-flight stages/output stores all done
    __syncthreads();
    // prologue: stage tile 0 into buffer 0
    {
      gload16(srcK0, Ks[0] + w * 1024);
      gload16(srcK1 + (size_t)0, Ks[0] + 4096 + w * 1024);
      gload16(srcV0, Vs[0] + w * 1024);
      gload16(srcV1 + (size_t)0, Vs[0] + 4096 + w * 1024);
    }

#pragma unroll 1
    for (int kt = 0; kt < nkt; ++kt) {
      const int par = kt & 1;
      // issue next tile's stage (redundant re-stage on last iter keeps vmcnt uniform)
      const int ktn = (kt + 1 < nkt) ? (kt + 1) : kt;
      gload16(srcK0 + (size_t)ktn * 8192, Ks[par ^ 1] + w * 1024);
      gload16(srcK1 + (size_t)ktn * 8192, Ks[par ^ 1] + 4096 + w * 1024);
      gload16(srcV0 + ktn * 128, Vs[par ^ 1] + w * 1024);
      gload16(srcV1 + ktn * 128, Vs[par ^ 1] + 4096 + w * 1024);
      // wait current tile's 4 loads (leave next's 4 in flight), then sync
      asm volatile("s_waitcnt vmcnt(4)" ::: "memory");
      __builtin_amdgcn_s_barrier();

      const char* Kc = Ks[par];
      const char* Vc = Vs[par];

      // QK^T: 4 col fragments x (K=64 -> 2 MFMA)
      f32x4 s[4];
#pragma unroll
      for (int c = 0; c < 4; ++c) {
        const int r = c * 16 + l15;
        const int xr = (r & 7) << 4;
        const short8 kf0 = *(const short8*)(Kc + r * 128 + ((grp * 16) ^ xr));
        const short8 kf1 = *(const short8*)(Kc + r * 128 + ((64 + grp * 16) ^ xr));
        f32x4 z = (f32x4){0.f, 0.f, 0.f, 0.f};
        z = MFMA(qf0, kf0, z);
        z = MFMA(qf1, kf1, z);
        s[c] = z;
      }

      // online softmax (rows spread over 16 lanes: shfl_xor 1,2,4,8)
      const bool diag = (kt == qblk);
      float alpha[4], p[4][4];
#pragma unroll
      for (int j = 0; j < 4; ++j) {
        const int qg = qw + grp * 4 + j;
        float a[4];
#pragma unroll
        for (int c = 0; c < 4; ++c) {
          float av = s[c][j] * 0.125f;
          if (diag && (kt * 64 + c * 16 + l15 > qg)) av = -3.0e38f;
          a[c] = av;
        }
        float mx = fmaxf(fmaxf(a[0], a[1]), fmaxf(a[2], a[3]));
        mx = fmaxf(mx, __shfl_xor(mx, 1, 64));
        mx = fmaxf(mx, __shfl_xor(mx, 2, 64));
        mx = fmaxf(mx, __shfl_xor(mx, 4, 64));
        mx = fmaxf(mx, __shfl_xor(mx, 8, 64));
        const float mnew = fmaxf(mrun[j], mx);
        alpha[j] = __expf(mrun[j] - mnew);
        mrun[j] = mnew;
        float rs = 0.f;
#pragma unroll
        for (int c = 0; c < 4; ++c) {
          const float e = __expf(a[c] - mnew);
          p[c][j] = e;
          rs += e;
        }
        rs += __shfl_xor(rs, 1, 64);
        rs += __shfl_xor(rs, 2, 64);
        rs += __shfl_xor(rs, 4, 64);
        rs += __shfl_xor(rs, 8, 64);
        lrun[j] = lrun[j] * alpha[j] + rs;
      }
#pragma unroll
      for (int d = 0; d < 4; ++d)
#pragma unroll
        for (int j = 0; j < 4; ++j) o[d][j] *= alpha[j];

      // write P (swizzled), per-wave buffer; same-wave DS pipe keeps RAW order
#pragma unroll
      for (int j = 0; j < 4; ++j) {
        const int r = grp * 4 + j;
        const int xr = (r & 7) << 4;
        char* pr = Pw + r * 128;
#pragma unroll
        for (int c = 0; c < 4; ++c)
          *(unsigned short*)(pr + (((c * 16 + l15) * 2) ^ xr)) = f2b(p[c][j]);
      }
      // PV: A = P rows, B = V^T rows (d as output col)
      const int xp = (l15 & 7) << 4;
      const short8 pa0 = *(const short8*)(Pw + l15 * 128 + ((grp * 16) ^ xp));
      const short8 pa1 = *(const short8*)(Pw + l15 * 128 + ((64 + grp * 16) ^ xp));
#pragma unroll
      for (int db = 0; db < 4; ++db) {
        const int rv = db * 16 + l15;
        const int xv = (rv & 7) << 4;
        const short8 vf0 = *(const short8*)(Vc + rv * 128 + ((grp * 16) ^ xv));
        const short8 vf1 = *(const short8*)(Vc + rv * 128 + ((64 + grp * 16) ^ xv));
        o[db] = MFMA(pa0, vf0, o[db]);
        o[db] = MFMA(pa1, vf1, o[db]);
      }
      // all lgkm (ds_read) results consumed above; safe to let next iter's
      // stage overwrite buf[par^1... wait handled by this barrier:
      __builtin_amdgcn_s_barrier();
    }

#pragma unroll
    for (int db = 0; db < 4; ++db)
#pragma unroll
      for (int j = 0; j < 4; ++j) {
        const float valo = o[db][j] / lrun[j];
        const size_t rowo = (size_t)bq * 2048 + qw + grp * 4 + j;
        yh[rowo * 1024 + hh * 64 + db * 16 + l15] = f2b(valo);
      }
  }
}

extern "C" void kernel_launch(void* const* d_in, const int* in_sizes, int n_in,
                              void* d_out, int out_size, void* d_ws, size_t ws_size,
                              hipStream_t stream) {
  const float* x = (const float*)d_in[0];
  const float* wqkv = (const float*)d_in[1];
  const float* wo = (const float*)d_in[2];
  const float* w1 = (const float*)d_in[3];
  const float* w2 = (const float*)d_in[4];
  const float* w3 = (const float*)d_in[5];
  const float* g1 = (const float*)d_in[6];
  const float* g2 = (const float*)d_in[7];

  char* ws = (char*)d_ws;
  unsigned short* wqkv_b = (unsigned short*)(ws + 0);         // 3072x1024
  unsigned short* wo_b = (unsigned short*)(ws + 6291456);     // 1024x1024
  unsigned short* w1_b = (unsigned short*)(ws + 8388608);     // 4096x1024
  unsigned short* w3_b = (unsigned short*)(ws + 16777216);    // 4096x1024
  unsigned short* w2_b = (unsigned short*)(ws + 25165824);    // 1024x4096
  float* x2 = (float*)(ws + 33554432);                        // f32 residual (16MB)
  float2* rtab = (float2*)(ws + 33554432);                    // RoPE table (aliases x2; dead before wo-gemm)
  unsigned short* yb = (unsigned short*)(ws + 50331648);      // 4096x1024 (both norms)
  unsigned short* qb = (unsigned short*)(ws + 58720256);      // (B,H,L,DH)
  unsigned short* kb = (unsigned short*)(ws + 67108864);
  unsigned short* vb = (unsigned short*)(ws + 75497472);
  unsigned short* vt = (unsigned short*)(ws + 83886080);      // V^T (B,H,DH,L)
  unsigned short* yh = vb;                                    // attn out reuses dead vb
  unsigned short* hb = (unsigned short*)(ws + 58720256);      // 4096x4096, reuses q/k/v/vt
  if (ws_size < 92274688) return;

  cvt_k<<<3072, 256, 0, stream>>>(wqkv, wqkv_b, 3145728);
  cvt_k<<<1024, 256, 0, stream>>>(wo, wo_b, 1048576);
  cvt_k<<<4096, 256, 0, stream>>>(w1, w1_b, 4194304);
  cvt_k<<<4096, 256, 0, stream>>>(w3, w3_b, 4194304);
  cvt_k<<<4096, 256, 0, stream>>>(w2, w2_b, 4194304);
  rope_k<<<256, 256, 0, stream>>>(rtab);

  rms_k<<<4096, 256, 0, stream>>>(x, g1, yb);
  gemm_bt<0><<<dim3(24, 32), 256, 0, stream>>>(yb, wqkv_b, nullptr, 4096, 3072, 1024,
                                               nullptr, nullptr, qb, kb, vb, nullptr, rtab);
  vtr_k<<<dim3(32, 32), 256, 0, stream>>>(vb, vt);
  attn_k<<<dim3(16, 32), 256, 0, stream>>>(qb, kb, vt, yh);
  gemm_bt<1><<<dim3(8, 32), 256, 0, stream>>>(yh, wo_b, nullptr, 4096, 1024, 1024,
                                              x2, x, nullptr, nullptr, nullptr, nullptr, nullptr);
  rms_k<<<4096, 256, 0, stream>>>(x2, g2, yb);
  gemm_bt<2><<<dim3(64, 32), 256, 0, stream>>>(yb, w1_b, w3_b, 4096, 4096, 1024,
                                               nullptr, nullptr, nullptr, nullptr, nullptr, hb, nullptr);
  gemm_bt<1><<<dim3(8, 32), 256, 0, stream>>>(hb, w2_b, nullptr, 4096, 1024, 4096,
                                              (float*)d_out, x2, nullptr, nullptr, nullptr, nullptr, nullptr);
}